// Round 7
// baseline (113.403 us; speedup 1.0000x reference)
//
#include <hip/hip_runtime.h>
#include <hip/hip_fp16.h>

#define ACN_EPS   0.001f
#define ACN_LOG2E 1.4426950408889634f
#define ACN_LN2   0.6931471805599453f
#define TBL_N     512
#define TBL_LO    -8.0f
#define TBL_SCALE 32.0f       // TBL_N / (HI-LO) = 512/16
#define TBL_OFF   256.0f      // -TBL_LO * TBL_SCALE
#define TBL_MAX_T 511.999f

typedef float v4f  __attribute__((ext_vector_type(4)));
typedef unsigned int u32;

// ---------------------------------------------------------------------------
// F(x) in exp2-folded form (no divides; exact exponents).
// ---------------------------------------------------------------------------
__device__ __forceinline__ float acn_F_fast(float x, const float* mu,
                                            const float* s1, const float* lp,
                                            const float* s2, const float* lw) {
    float denom = 0.0f, S = 0.0f;
#pragma unroll
    for (int k = 0; k < 8; ++k) {
        float d  = x - mu[k];
        float d2 = d * d;
        denom += __builtin_amdgcn_exp2f(fmaf(s1[k], d2, lp[k]));
        S = fmaf(__builtin_amdgcn_exp2f(fmaf(s2[k], d2, lw[k])), d, S);
    }
    return S * __builtin_amdgcn_rcpf(denom + ACN_EPS);
}

__device__ __forceinline__ u32 acn_pack(float y, float dy) {
    __half2 hv = __halves2half2(__float2half(y), __float2half(dy));
    return *(const u32*)&hv;
}

__device__ __forceinline__ float acn_interp(const u32* tbl, float xx) {
    float t  = fmaf(xx, TBL_SCALE, TBL_OFF);
    t        = __builtin_amdgcn_fmed3f(t, 0.0f, TBL_MAX_T);
    int   ii = (int)t;
    float f  = t - (float)ii;
    u32 u = tbl[ii];
    __half2 hv = *(const __half2*)&u;
    return fmaf(__high2float(hv), f, __low2float(hv));
}

__device__ __forceinline__ v4f acn_interp4(const u32* tbl, v4f xv) {
    v4f r;
    r.x = acn_interp(tbl, xv.x);
    r.y = acn_interp(tbl, xv.y);
    r.z = acn_interp(tbl, xv.z);
    r.w = acn_interp(tbl, xv.w);
    return r;
}

// ---------------------------------------------------------------------------
// Single fused kernel (R6 post-mortem: kernel-launch + build exec + global
// table round-trip were the residual ~5 us). Each block redundantly builds
// the 512-interval f16x2 piecewise-linear table in LDS (~1000 cyc/wave of
// VALU, hidden behind the first prefetched x loads — the kernel is HBM-bound
// with ~20x VALU slack), then streams x -> interp -> out.
// ---------------------------------------------------------------------------
__global__ __launch_bounds__(256) void acn_fused(const v4f* __restrict__ x,
                                                 v4f* __restrict__ out,
                                                 const float* __restrict__ mean,
                                                 const float* __restrict__ variance,
                                                 const float* __restrict__ prior,
                                                 int n4) {
    __shared__ u32 tbl[TBL_N];

    const int Tn   = gridDim.x * blockDim.x;
    const int idx  = blockIdx.x * blockDim.x + threadIdx.x;
    const bool fast = (n4 == 8 * Tn);

    // Issue the first global loads BEFORE the table build so HBM streams
    // during the ~1000-cycle build.
    v4f a, b;
    if (fast) { a = x[idx]; b = x[idx + Tn]; }

    // ---- per-block table build: thread t covers intervals 2t, 2t+1 ----
    {
        float mu[8], s1[8], lp[8], s2[8], lw[8], e[8];
        float mx = -1e30f;
#pragma unroll
        for (int k = 0; k < 8; ++k) { e[k] = prior[k]; mx = fmaxf(mx, e[k]); }
        float sum = 0.0f;
#pragma unroll
        for (int k = 0; k < 8; ++k) {
            e[k] = __builtin_amdgcn_exp2f((e[k] - mx) * ACN_LOG2E);
            sum += e[k];
        }
        float rs = __builtin_amdgcn_rcpf(sum);
#pragma unroll
        for (int k = 0; k < 8; ++k) {
            float pk = e[k] * rs;                                 // softmax
            float v  = __builtin_amdgcn_logf(1.0f +
                         __builtin_amdgcn_exp2f(variance[k] * ACN_LOG2E)) * ACN_LN2;
            float ve = v + ACN_EPS;
            float rv  = __builtin_amdgcn_rcpf(v);
            float rve = __builtin_amdgcn_rcpf(ve);
            mu[k] = mean[k];
            s1[k] = -0.5f * ACN_LOG2E * rv * rv;
            s2[k] = -0.5f * ACN_LOG2E * rve * rve;
            lp[k] = __builtin_amdgcn_logf(pk);
            lw[k] = lp[k] - 0.5f * __builtin_amdgcn_logf(pk + ACN_EPS)
                          - 0.5f * __builtin_amdgcn_logf(ve);
        }

        const float h = 1.0f / TBL_SCALE;
        int   t  = threadIdx.x;            // 0..255 -> intervals 2t, 2t+1
        float x0 = TBL_LO + (float)(2 * t) * h;
        float y0 = acn_F_fast(x0,            mu, s1, lp, s2, lw);
        float y1 = acn_F_fast(x0 + h,        mu, s1, lp, s2, lw);
        float y2 = acn_F_fast(x0 + 2.0f * h, mu, s1, lp, s2, lw);
        tbl[2 * t]     = acn_pack(y0, y1 - y0);
        tbl[2 * t + 1] = acn_pack(y1, y2 - y1);
    }
    __syncthreads();

    // ---- streaming interp ----
    if (fast) {
#pragma unroll
        for (int c = 0; c < 4; ++c) {
            const int i = idx + c * 2 * Tn;
            v4f an, bn;
            if (c < 3) {                 // prefetch next pair before compute
                an = x[i + 2 * Tn];
                bn = x[i + 3 * Tn];
            }
            __builtin_nontemporal_store(acn_interp4(tbl, a), &out[i]);
            __builtin_nontemporal_store(acn_interp4(tbl, b), &out[i + Tn]);
            if (c < 3) { a = an; b = bn; }
        }
    } else {
        for (int i = idx; i < n4; i += Tn) {
            __builtin_nontemporal_store(acn_interp4(tbl, x[i]), &out[i]);
        }
    }
}

extern "C" void kernel_launch(void* const* d_in, const int* in_sizes, int n_in,
                              void* d_out, int out_size, void* d_ws, size_t ws_size,
                              hipStream_t stream) {
    const float* x        = (const float*)d_in[0];
    const float* mean     = (const float*)d_in[1];
    const float* variance = (const float*)d_in[2];
    const float* prior    = (const float*)d_in[3];
    float* out = (float*)d_out;
    (void)d_ws; (void)ws_size;

    int n4 = out_size / 4;        // 4,194,304 = 8 * (2048*256)
    const int block = 256;
    const int grid  = 2048;       // 8 blocks/CU; LDS 2 KB/block
    acn_fused<<<grid, block, 0, stream>>>((const v4f*)x, (v4f*)out,
                                          mean, variance, prior, n4);
}